// Round 1
// baseline (1123.722 us; speedup 1.0000x reference)
//
#include <hip/hip_runtime.h>

typedef _Float16 f16;
typedef _Float16 half8 __attribute__((ext_vector_type(8)));
typedef float f32x4 __attribute__((ext_vector_type(4)));

#define BATCH 16
#define NQ 64
#define SL 4096
#define DH 128

// ---------------------------------------------------------------------------
// Kernel P: convert + transpose K,V  (f32 [b][n][d]) -> f16 [b][d][n]
// grid 1024 = 16 b * 2 tensors * 32 n-chunks(128), block 256 (=128 d * 2 nh)
// ---------------------------------------------------------------------------
__global__ __launch_bounds__(256) void kprep(const float* __restrict__ Kg,
                                             const float* __restrict__ Vg,
                                             f16* __restrict__ Kt,
                                             f16* __restrict__ Vt) {
  const int blk = blockIdx.x;
  const int b = blk >> 6;
  const int tensor = (blk >> 5) & 1;
  const int chunk = blk & 31;
  const float* src = tensor ? Vg : Kg;
  f16* dst = tensor ? Vt : Kt;
  const int t = threadIdx.x;
  const int d = t & 127;
  const int n0 = chunk * 128 + (t >> 7) * 64;
  const float* s = src + ((size_t)b * SL + n0) * DH + d;
  f16* o = dst + ((size_t)b * DH + d) * SL + n0;
  for (int j0 = 0; j0 < 64; j0 += 8) {
    half8 tmp;
#pragma unroll
    for (int j = 0; j < 8; ++j) tmp[j] = (f16)s[(size_t)(j0 + j) * DH];
    *(half8*)(o + j0) = tmp;
  }
}

// ---------------------------------------------------------------------------
// Kernel S: scores + exp + denominator.  block = (b, group of 8 q), 512 thr.
// wave w handles n-slice [w*512, w*512+512) for all 8 q (K read once/block).
// E[b][q][n] = exp(scale * Q.K[n]);  denom[b][q] = sum_n E  (deterministic).
// ---------------------------------------------------------------------------
__global__ __launch_bounds__(512) void kscore(const float* __restrict__ Q,
                                              const float* __restrict__ K,
                                              float* __restrict__ E,
                                              float* __restrict__ denom) {
  __shared__ __align__(16) float Qs[8][128];
  __shared__ float wsum[8][8];
  const int blk = blockIdx.x;
  const int b = blk >> 3;
  const int q0 = (blk & 7) * 8;
  const int t = threadIdx.x;
  for (int i = t; i < 1024; i += 512) {
    const int q = i >> 7, d = i & 127;
    Qs[q][d] = Q[((size_t)b * NQ + q0 + q) * DH + d];
  }
  __syncthreads();
  const int w = t >> 6, lane = t & 63;
  const float scale = 0.08838834764831845f;  // 1/sqrt(128)
  float ed[8] = {0.f, 0.f, 0.f, 0.f, 0.f, 0.f, 0.f, 0.f};
  for (int it = 0; it < 8; ++it) {
    const int n = w * 512 + it * 64 + lane;
    const float* kp = K + ((size_t)b * SL + n) * DH;
    f32x4 acc[8] = {};
    for (int c = 0; c < 32; ++c) {
      const f32x4 kc = *(const f32x4*)(kp + 4 * c);
#pragma unroll
      for (int q = 0; q < 8; ++q) {
        const f32x4 qc = *(const f32x4*)&Qs[q][4 * c];
        acc[q] += kc * qc;
      }
    }
#pragma unroll
    for (int q = 0; q < 8; ++q) {
      const float s = acc[q][0] + acc[q][1] + acc[q][2] + acc[q][3];
      const float eq = __expf(s * scale);
      E[((size_t)b * NQ + q0 + q) * SL + n] = eq;
      ed[q] += eq;
    }
  }
#pragma unroll
  for (int q = 0; q < 8; ++q) {
    float v = ed[q];
    for (int off = 32; off > 0; off >>= 1) v += __shfl_down(v, off);
    if (lane == 0) wsum[w][q] = v;
  }
  __syncthreads();
  if (t < 8) {
    float s = 0.f;
    for (int w2 = 0; w2 < 8; ++w2) s += wsum[w2][t];
    denom[b * NQ + q0 + t] = s;
  }
}

// ---------------------------------------------------------------------------
// Kernel G: per (b, 2 q's):  T[v][k] = sum_n E_n*V[n][v]*K[n][k]   (MFMA f16)
// out = scale*invd*(T - invd*EV[v]*EK[k]).  EV/EK accumulated during staging.
// 4 waves, each a 64x64 quadrant; BK=32; LDS rows padded to 40 halves (80 B).
// ---------------------------------------------------------------------------
__global__ __launch_bounds__(256, 2) void kjac(const f16* __restrict__ Vt,
                                               const f16* __restrict__ Kt,
                                               const float* __restrict__ E,
                                               const float* __restrict__ denom,
                                               float* __restrict__ out) {
  __shared__ __align__(16) f16 Ul[2][128][40];
  __shared__ __align__(16) f16 Kl[128][40];
  __shared__ float EVl[2][128];
  __shared__ float EKl[2][128];

  const int blk = blockIdx.x;
  const int b = blk >> 5;
  const int q0 = (blk & 31) * 2;
  const int t = threadIdx.x;
  const int c = t & 3;        // n-chunk within BK=32 (8 elems each)
  const int vr = t >> 2;      // [0,64)
  const int w = t >> 6;
  const int l = t & 63;
  const int Mb = (w >> 1) * 64;
  const int Nb = (w & 1) * 64;
  const int lr = l & 15;
  const int lk = (l >> 4) * 8;

  const f16* vtb = Vt + (size_t)b * DH * SL;
  const f16* ktb = Kt + (size_t)b * DH * SL;
  const float* Eb = E + ((size_t)b * NQ + q0) * SL;

  f32x4 acc[2][4][4] = {};
  float evp[4] = {0.f, 0.f, 0.f, 0.f};
  float ekp[2][2] = {{0.f, 0.f}, {0.f, 0.f}};

  for (int n0 = 0; n0 < SL; n0 += 32) {
    const int nc = n0 + c * 8;
    f32x4 e[2][2];
#pragma unroll
    for (int q = 0; q < 2; ++q) {
      e[q][0] = *(const f32x4*)(Eb + (size_t)q * SL + nc);
      e[q][1] = *(const f32x4*)(Eb + (size_t)q * SL + nc + 4);
    }
    // stage U = E*V (per q) rows vr, vr+64 ; accumulate EV partials
#pragma unroll
    for (int i = 0; i < 4; ++i) {
      const int q = i >> 1;
      const int v = vr + (i & 1) * 64;
      const half8 vh = *(const half8*)(vtb + (size_t)v * SL + nc);
      half8 uh;
      float ev = 0.f;
#pragma unroll
      for (int j = 0; j < 4; ++j) {
        const float p0 = e[q][0][j] * (float)vh[j];
        const float p1 = e[q][1][j] * (float)vh[j + 4];
        uh[j] = (f16)p0;
        uh[j + 4] = (f16)p1;
        ev += p0 + p1;
      }
      *(half8*)&Ul[q][v][c * 8] = uh;
      evp[i] += ev;
    }
    // stage K tile ; accumulate EK partials (per q)
#pragma unroll
    for (int i = 0; i < 2; ++i) {
      const int k = vr + i * 64;
      const half8 kh = *(const half8*)(ktb + (size_t)k * SL + nc);
      *(half8*)&Kl[k][c * 8] = kh;
#pragma unroll
      for (int q = 0; q < 2; ++q) {
        float s = 0.f;
#pragma unroll
        for (int j = 0; j < 4; ++j)
          s += e[q][0][j] * (float)kh[j] + e[q][1][j] * (float)kh[j + 4];
        ekp[i][q] += s;
      }
    }
    __syncthreads();

    half8 bf[4];
#pragma unroll
    for (int j = 0; j < 4; ++j)
      bf[j] = *(const half8*)&Kl[Nb + j * 16 + lr][lk];
#pragma unroll
    for (int q = 0; q < 2; ++q) {
      half8 af[4];
#pragma unroll
      for (int i = 0; i < 4; ++i)
        af[i] = *(const half8*)&Ul[q][Mb + i * 16 + lr][lk];
#pragma unroll
      for (int i = 0; i < 4; ++i)
#pragma unroll
        for (int j = 0; j < 4; ++j)
          acc[q][i][j] = __builtin_amdgcn_mfma_f32_16x16x32_f16(
              af[i], bf[j], acc[q][i][j], 0, 0, 0);
    }
    __syncthreads();
  }

  // reduce EV/EK partials across the 4 c-chunks (adjacent lanes) -> LDS
#pragma unroll
  for (int i = 0; i < 4; ++i) {
    float v = evp[i];
    v += __shfl_xor(v, 1);
    v += __shfl_xor(v, 2);
    if (c == 0) EVl[i >> 1][vr + (i & 1) * 64] = v;
  }
#pragma unroll
  for (int i = 0; i < 2; ++i)
#pragma unroll
    for (int q = 0; q < 2; ++q) {
      float v = ekp[i][q];
      v += __shfl_xor(v, 1);
      v += __shfl_xor(v, 2);
      if (c == 0) EKl[q][vr + i * 64] = v;
    }
  __syncthreads();

  const float scale = 0.08838834764831845f;
#pragma unroll
  for (int q = 0; q < 2; ++q) {
    const float invd = 1.0f / denom[b * NQ + q0 + q];
    float* ob = out + ((size_t)(b * NQ + q0 + q)) * DH * DH;
#pragma unroll
    for (int i = 0; i < 4; ++i) {
#pragma unroll
      for (int r = 0; r < 4; ++r) {
        const int row = Mb + i * 16 + (l >> 4) * 4 + r;
        const float ev = EVl[q][row];
#pragma unroll
        for (int j = 0; j < 4; ++j) {
          const int col = Nb + j * 16 + lr;
          const float ek = EKl[q][col];
          ob[(size_t)row * DH + col] =
              scale * invd * (acc[q][i][j][r] - invd * ev * ek);
        }
      }
    }
  }
}

extern "C" void kernel_launch(void* const* d_in, const int* in_sizes, int n_in,
                              void* d_out, int out_size, void* d_ws,
                              size_t ws_size, hipStream_t stream) {
  const float* Q = (const float*)d_in[0];
  const float* K = (const float*)d_in[1];
  const float* V = (const float*)d_in[2];
  float* out = (float*)d_out;

  // workspace layout: Vt f16 (16.8MB) | Kt f16 (16.8MB) | E f32 (16.8MB) | denom f32
  f16* Vt = (f16*)d_ws;
  f16* Kt = Vt + (size_t)BATCH * DH * SL;
  float* E = (float*)(Kt + (size_t)BATCH * DH * SL);
  float* denom = E + (size_t)BATCH * NQ * SL;

  kprep<<<1024, 256, 0, stream>>>(K, V, Kt, Vt);
  kscore<<<128, 512, 0, stream>>>(Q, K, E, denom);
  kjac<<<512, 256, 0, stream>>>(Vt, Kt, E, denom, out);
}

// Round 2
// 259.964 us; speedup vs baseline: 4.3226x; 4.3226x over previous
//
#include <hip/hip_runtime.h>

typedef _Float16 f16;
typedef _Float16 half4 __attribute__((ext_vector_type(4)));
typedef _Float16 half8 __attribute__((ext_vector_type(8)));
typedef float f32x4 __attribute__((ext_vector_type(4)));

#define BATCH 16
#define NQ 64
#define SL 4096
#define DH 128

// ---------------------------------------------------------------------------
// Kernel P: convert + transpose K,V (f32 [b][n][d]) -> f16 [b][d][n]
// LDS-transpose tile 128n x 128d so both global reads AND writes coalesce.
// grid 1024 = 16 b * 2 tensors * 32 n-chunks(128), block 256.
// ---------------------------------------------------------------------------
__global__ __launch_bounds__(256) void kprep(const float* __restrict__ Kg,
                                             const float* __restrict__ Vg,
                                             f16* __restrict__ Kt,
                                             f16* __restrict__ Vt) {
  __shared__ f16 Ld[128][130];  // row stride 260B: bank stride 65 == 1 mod 32
  const int blk = blockIdx.x;
  const int b = blk >> 6;
  const int tensor = (blk >> 5) & 1;
  const int chunk = blk & 31;
  const float* src = tensor ? Vg : Kg;
  f16* dst = tensor ? Vt : Kt;
  const int t = threadIdx.x;
  const int n0 = chunk * 128;
  {
    const int d = t & 127;
    const int nl = t >> 7;  // 0..1
    const float* s = src + ((size_t)b * SL + n0 + nl) * DH + d;
    for (int it = 0; it < 64; ++it)
      Ld[d][nl + it * 2] = (f16)s[(size_t)it * 2 * DH];
  }
  __syncthreads();
  {
    const int nl = (t & 15) * 8;
    const int d0 = t >> 4;  // 0..15
    f16* o = dst + (size_t)b * DH * SL + n0;
    for (int it = 0; it < 8; ++it) {
      const int d = d0 + it * 16;
      *(half8*)(o + (size_t)d * SL + nl) = *(const half8*)&Ld[d][nl];
    }
  }
}

// ---------------------------------------------------------------------------
// Kernel S: E[b][q][n] = exp(scale * Q.K[n]).  Lane owns 4 consecutive n
// (coalesced half4 loads from Kt), Q broadcast from LDS, 32 ind. FMAs/load.
// grid = 16 b * 16 nchunk(256) * 2 qgroup(32) = 512 blocks, 256 thr (4 waves),
// wave w handles 8 q's.
// ---------------------------------------------------------------------------
__global__ __launch_bounds__(256) void kscore(const float* __restrict__ Q,
                                              const f16* __restrict__ Kt,
                                              float* __restrict__ E) {
  __shared__ float Qs[32][128];
  const int blk = blockIdx.x;
  const int b = blk >> 5;
  const int chunk = (blk >> 1) & 15;
  const int qg = blk & 1;
  const int t = threadIdx.x;
  for (int i = t; i < 32 * 128; i += 256) {
    const int q = i >> 7, d = i & 127;
    Qs[q][d] = Q[((size_t)b * NQ + qg * 32 + q) * DH + d];
  }
  __syncthreads();
  const int w = t >> 6, lane = t & 63;
  const int n = chunk * 256 + lane * 4;
  const f16* kp = Kt + (size_t)b * DH * SL + n;
  float acc[8][4] = {};
#pragma unroll 4
  for (int d = 0; d < DH; ++d) {
    const half4 kv = *(const half4*)(kp + (size_t)d * SL);
    const float k0 = (float)kv[0], k1 = (float)kv[1], k2 = (float)kv[2],
                k3 = (float)kv[3];
#pragma unroll
    for (int j = 0; j < 8; ++j) {
      const float qv = Qs[w * 8 + j][d];
      acc[j][0] += qv * k0;
      acc[j][1] += qv * k1;
      acc[j][2] += qv * k2;
      acc[j][3] += qv * k3;
    }
  }
  const float scale = 0.08838834764831845f;  // 1/sqrt(128)
#pragma unroll
  for (int j = 0; j < 8; ++j) {
    f32x4 e;
#pragma unroll
    for (int c = 0; c < 4; ++c) e[c] = __expf(acc[j][c] * scale);
    *(f32x4*)&E[((size_t)b * NQ + qg * 32 + w * 8 + j) * SL + n] = e;
  }
}

// ---------------------------------------------------------------------------
// Kernel R: denom[b][q] = sum_n E[b][q][n].  One wave per (b,q) row.
// ---------------------------------------------------------------------------
__global__ __launch_bounds__(256) void kreduce(const float* __restrict__ E,
                                               float* __restrict__ denom) {
  const int gw = blockIdx.x * 4 + (threadIdx.x >> 6);
  const int lane = threadIdx.x & 63;
  const float* e = E + (size_t)gw * SL;
  f32x4 s4 = {0.f, 0.f, 0.f, 0.f};
#pragma unroll
  for (int i = 0; i < 16; ++i) s4 += *(const f32x4*)(e + i * 256 + lane * 4);
  float s = s4[0] + s4[1] + s4[2] + s4[3];
  for (int off = 1; off < 64; off <<= 1) s += __shfl_xor(s, off);
  if (lane == 0) denom[gw] = s;
}

// ---------------------------------------------------------------------------
// Kernel G: per (b, 2 q's):  T[v][k] = sum_n E_n*V[n][v]*K[n][k]   (MFMA f16)
// out = scale*invd*(T - invd*EV[v]*EK[k]).  EV/EK accumulated during staging.
// 4 waves, each a 64x64 quadrant; BK=32; LDS rows padded to 40 halves (80 B).
// ---------------------------------------------------------------------------
__global__ __launch_bounds__(256, 2) void kjac(const f16* __restrict__ Vt,
                                               const f16* __restrict__ Kt,
                                               const float* __restrict__ E,
                                               const float* __restrict__ denom,
                                               float* __restrict__ out) {
  __shared__ __align__(16) f16 Ul[2][128][40];
  __shared__ __align__(16) f16 Kl[128][40];
  __shared__ float EVl[2][128];
  __shared__ float EKl[2][128];

  const int blk = blockIdx.x;
  const int b = blk >> 5;
  const int q0 = (blk & 31) * 2;
  const int t = threadIdx.x;
  const int c = t & 3;        // n-chunk within BK=32 (8 elems each)
  const int vr = t >> 2;      // [0,64)
  const int w = t >> 6;
  const int l = t & 63;
  const int Mb = (w >> 1) * 64;
  const int Nb = (w & 1) * 64;
  const int lr = l & 15;
  const int lk = (l >> 4) * 8;

  const f16* vtb = Vt + (size_t)b * DH * SL;
  const f16* ktb = Kt + (size_t)b * DH * SL;
  const float* Eb = E + ((size_t)b * NQ + q0) * SL;

  f32x4 acc[2][4][4] = {};
  float evp[4] = {0.f, 0.f, 0.f, 0.f};
  float ekp[2][2] = {{0.f, 0.f}, {0.f, 0.f}};

  for (int n0 = 0; n0 < SL; n0 += 32) {
    const int nc = n0 + c * 8;
    f32x4 e[2][2];
#pragma unroll
    for (int q = 0; q < 2; ++q) {
      e[q][0] = *(const f32x4*)(Eb + (size_t)q * SL + nc);
      e[q][1] = *(const f32x4*)(Eb + (size_t)q * SL + nc + 4);
    }
    // stage U = E*V (per q) rows vr, vr+64 ; accumulate EV partials
#pragma unroll
    for (int i = 0; i < 4; ++i) {
      const int q = i >> 1;
      const int v = vr + (i & 1) * 64;
      const half8 vh = *(const half8*)(vtb + (size_t)v * SL + nc);
      half8 uh;
      float ev = 0.f;
#pragma unroll
      for (int j = 0; j < 4; ++j) {
        const float p0 = e[q][0][j] * (float)vh[j];
        const float p1 = e[q][1][j] * (float)vh[j + 4];
        uh[j] = (f16)p0;
        uh[j + 4] = (f16)p1;
        ev += p0 + p1;
      }
      *(half8*)&Ul[q][v][c * 8] = uh;
      evp[i] += ev;
    }
    // stage K tile ; accumulate EK partials (per q)
#pragma unroll
    for (int i = 0; i < 2; ++i) {
      const int k = vr + i * 64;
      const half8 kh = *(const half8*)(ktb + (size_t)k * SL + nc);
      *(half8*)&Kl[k][c * 8] = kh;
#pragma unroll
      for (int q = 0; q < 2; ++q) {
        float s = 0.f;
#pragma unroll
        for (int j = 0; j < 4; ++j)
          s += e[q][0][j] * (float)kh[j] + e[q][1][j] * (float)kh[j + 4];
        ekp[i][q] += s;
      }
    }
    __syncthreads();

    half8 bf[4];
#pragma unroll
    for (int j = 0; j < 4; ++j)
      bf[j] = *(const half8*)&Kl[Nb + j * 16 + lr][lk];
#pragma unroll
    for (int q = 0; q < 2; ++q) {
      half8 af[4];
#pragma unroll
      for (int i = 0; i < 4; ++i)
        af[i] = *(const half8*)&Ul[q][Mb + i * 16 + lr][lk];
#pragma unroll
      for (int i = 0; i < 4; ++i)
#pragma unroll
        for (int j = 0; j < 4; ++j)
          acc[q][i][j] = __builtin_amdgcn_mfma_f32_16x16x32_f16(
              af[i], bf[j], acc[q][i][j], 0, 0, 0);
    }
    __syncthreads();
  }

  // reduce EV/EK partials across the 4 c-chunks (adjacent lanes) -> LDS
#pragma unroll
  for (int i = 0; i < 4; ++i) {
    float v = evp[i];
    v += __shfl_xor(v, 1);
    v += __shfl_xor(v, 2);
    if (c == 0) EVl[i >> 1][vr + (i & 1) * 64] = v;
  }
#pragma unroll
  for (int i = 0; i < 2; ++i)
#pragma unroll
    for (int q = 0; q < 2; ++q) {
      float v = ekp[i][q];
      v += __shfl_xor(v, 1);
      v += __shfl_xor(v, 2);
      if (c == 0) EKl[q][vr + i * 64] = v;
    }
  __syncthreads();

  const float scale = 0.08838834764831845f;
#pragma unroll
  for (int q = 0; q < 2; ++q) {
    const float invd = 1.0f / denom[b * NQ + q0 + q];
    float* ob = out + ((size_t)(b * NQ + q0 + q)) * DH * DH;
#pragma unroll
    for (int i = 0; i < 4; ++i) {
#pragma unroll
      for (int r = 0; r < 4; ++r) {
        const int row = Mb + i * 16 + (l >> 4) * 4 + r;
        const float ev = EVl[q][row];
#pragma unroll
        for (int j = 0; j < 4; ++j) {
          const int col = Nb + j * 16 + lr;
          const float ek = EKl[q][col];
          ob[(size_t)row * DH + col] =
              scale * invd * (acc[q][i][j][r] - invd * ev * ek);
        }
      }
    }
  }
}

extern "C" void kernel_launch(void* const* d_in, const int* in_sizes, int n_in,
                              void* d_out, int out_size, void* d_ws,
                              size_t ws_size, hipStream_t stream) {
  const float* Q = (const float*)d_in[0];
  const float* K = (const float*)d_in[1];
  const float* V = (const float*)d_in[2];
  float* out = (float*)d_out;

  // workspace: Vt f16 (16.8MB) | Kt f16 (16.8MB) | E f32 (16.8MB) | denom f32
  f16* Vt = (f16*)d_ws;
  f16* Kt = Vt + (size_t)BATCH * DH * SL;
  float* E = (float*)(Kt + (size_t)BATCH * DH * SL);
  float* denom = E + (size_t)BATCH * NQ * SL;

  kprep<<<1024, 256, 0, stream>>>(K, V, Kt, Vt);
  kscore<<<512, 256, 0, stream>>>(Q, Kt, E);
  kreduce<<<256, 256, 0, stream>>>(E, denom);
  kjac<<<512, 256, 0, stream>>>(Vt, Kt, E, denom, out);
}

// Round 3
// 244.041 us; speedup vs baseline: 4.6046x; 1.0652x over previous
//
#include <hip/hip_runtime.h>
#include <stdint.h>

typedef _Float16 f16;
typedef _Float16 half8 __attribute__((ext_vector_type(8)));
typedef float f32x4 __attribute__((ext_vector_type(4)));

#define BATCH 16
#define NQ 64
#define SL 4096
#define DH 128
#define NT (SL / 32)  // 128 n-tiles of 32

// Tiled f16 layout for Kt/Vt, per b (halves):
//   off(d, n) = (n>>5)*4096 + (d>>4)*512 + ((n>>3)&3)*128 + (d&15)*8 + (n&7)
// A fragment read (16x16x32 MFMA) is then LDS/global  base + lane*16 bytes.

typedef __attribute__((address_space(3))) uint8_t lds8_t;
typedef __attribute__((address_space(1))) uint8_t glb8_t;

__device__ __forceinline__ void gload16(const void* g, void* l) {
  __builtin_amdgcn_global_load_lds((const glb8_t*)g, (lds8_t*)l, 16, 0, 0);
}

// ---------------------------------------------------------------------------
// Kernel P: convert f32 [b][n][d] -> f16 tiled [b][(d,n) tiled]
// grid 1024 = 16 b * 2 tensors * 32 n-chunks(128), block 256.
// ---------------------------------------------------------------------------
__global__ __launch_bounds__(256) void kprep(const float* __restrict__ Kg,
                                             const float* __restrict__ Vg,
                                             f16* __restrict__ Kt,
                                             f16* __restrict__ Vt) {
  __shared__ f16 Ld[128][130];
  const int blk = blockIdx.x;
  const int b = blk >> 6;
  const int tensor = (blk >> 5) & 1;
  const int chunk = blk & 31;
  const float* src = tensor ? Vg : Kg;
  f16* dst = tensor ? Vt : Kt;
  const int t = threadIdx.x;
  const int n0 = chunk * 128;
  {
    const int d = t & 127;
    const int nl = t >> 7;  // 0..1
    const float* s = src + ((size_t)b * SL + n0 + nl) * DH + d;
    for (int it = 0; it < 64; ++it)
      Ld[d][nl + it * 2] = (f16)s[(size_t)it * 2 * DH];
  }
  __syncthreads();
  {
    const int r = t & 15;
    const int kc = (t >> 4) & 3;
    const int w = t >> 6;
    char* dstb = (char*)(dst + (size_t)b * DH * SL);
#pragma unroll
    for (int tl = 0; tl < 4; ++tl)
#pragma unroll
      for (int hh = 0; hh < 2; ++hh) {
        const int dhi = w + hh * 4;
        const int d = dhi * 16 + r;
        const int nl = tl * 32 + kc * 8;
        const half8 v = *(const half8*)&Ld[d][nl];
        *(half8*)(dstb + (size_t)(chunk * 4 + tl) * 8192 + dhi * 1024 +
                  kc * 256 + r * 16) = v;
      }
  }
}

// ---------------------------------------------------------------------------
// Kernel S: E[b][q][n] = (f16)exp(scale * Q.K[n]).  Reads tiled Kt.
// grid 512 = b(16) * qg(8 q's; 8) * ns(1024 n; 4); block 256.
// wave w: q-quarter (w>>1)*4, n-half (w&1)*512; lane owns 8 consecutive n.
// ---------------------------------------------------------------------------
__global__ __launch_bounds__(256) void kscore(const float* __restrict__ Q,
                                              const f16* __restrict__ Kt,
                                              f16* __restrict__ E) {
  __shared__ float Qs[8][128];
  const int blk = blockIdx.x;
  const int b = blk >> 5;
  const int qg = (blk >> 2) & 7;
  const int ns = blk & 3;
  const int t = threadIdx.x;
  for (int i = t; i < 8 * 128; i += 256)
    Qs[i >> 7][i & 127] = Q[((size_t)b * NQ + qg * 8 + (i >> 7)) * DH + (i & 127)];
  __syncthreads();
  const int w = t >> 6, l = t & 63;
  const int q0 = (w >> 1) * 4;
  const int nbase = ns * 1024 + (w & 1) * 512 + l * 8;
  const f16* kb = Kt + (size_t)b * DH * SL + (size_t)(nbase >> 5) * 4096 +
                  (size_t)((nbase >> 3) & 3) * 128;
  float acc[4][8] = {};
  for (int d = 0; d < DH; ++d) {
    const half8 kv = *(const half8*)(kb + (d >> 4) * 512 + (d & 15) * 8);
    float kf[8];
#pragma unroll
    for (int j = 0; j < 8; ++j) kf[j] = (float)kv[j];
#pragma unroll
    for (int qi = 0; qi < 4; ++qi) {
      const float qv = Qs[q0 + qi][d];
#pragma unroll
      for (int j = 0; j < 8; ++j) acc[qi][j] += qv * kf[j];
    }
  }
  const float scl = 0.08838834764831845f;  // 1/sqrt(128)
#pragma unroll
  for (int qi = 0; qi < 4; ++qi) {
    half8 ev;
#pragma unroll
    for (int j = 0; j < 8; ++j) ev[j] = (f16)__expf(acc[qi][j] * scl);
    *(half8*)&E[((size_t)b * NQ + qg * 8 + q0 + qi) * SL + nbase] = ev;
  }
}

// ---------------------------------------------------------------------------
// Kernel R: denom[b][q] = sum_n E[b][q][n] (f16 in, f32 acc, deterministic)
// ---------------------------------------------------------------------------
__global__ __launch_bounds__(256) void kreduce(const f16* __restrict__ E,
                                               float* __restrict__ denom) {
  const int gw = blockIdx.x * 4 + (threadIdx.x >> 6);
  const int lane = threadIdx.x & 63;
  const f16* e = E + (size_t)gw * SL;
  float s = 0.f;
#pragma unroll
  for (int i = 0; i < 8; ++i) {
    const half8 h = *(const half8*)(e + i * 512 + lane * 8);
#pragma unroll
    for (int j = 0; j < 8; ++j) s += (float)h[j];
  }
  for (int off = 1; off < 64; off <<= 1) s += __shfl_xor(s, off);
  if (lane == 0) denom[gw] = s;
}

// ---------------------------------------------------------------------------
// Kernel EVK: EV[b][q][v] = sum_n E*V ; EK[b][q][k] = sum_n E*K  via MFMA.
// grid 128 = b(16) * tensor(2) * vhalf(2) * qhalf(2); block 256 (4 waves).
// wave w: row-subtile sv = vh*4+w (16 rows) x 32 q's (2 q-subtiles).
// ---------------------------------------------------------------------------
__global__ __launch_bounds__(256) void kev(const f16* __restrict__ Vt,
                                           const f16* __restrict__ Kt,
                                           const f16* __restrict__ E,
                                           float* __restrict__ EV,
                                           float* __restrict__ EK) {
  const int blk = blockIdx.x;
  const int b = blk >> 3;
  const int tensor = (blk >> 2) & 1;
  const int vh = (blk >> 1) & 1;
  const int qh = blk & 1;
  const char* src = (const char*)((tensor ? Kt : Vt) + (size_t)b * DH * SL);
  float* dst = (tensor ? EK : EV) + ((size_t)b * NQ + qh * 32) * DH;
  const f16* Eb = E + ((size_t)b * NQ + qh * 32) * SL;
  const int t = threadIdx.x, w = t >> 6, l = t & 63;
  const int sv = vh * 4 + w;
  f32x4 acc[2] = {};
  for (int n0 = 0; n0 < SL; n0 += 32) {
    const half8 a =
        *(const half8*)(src + (size_t)(n0 >> 5) * 8192 + sv * 1024 + l * 16);
    const half8 b0 = *(const half8*)(Eb + (size_t)(l & 15) * SL + n0 + (l >> 4) * 8);
    const half8 b1 =
        *(const half8*)(Eb + (size_t)((l & 15) + 16) * SL + n0 + (l >> 4) * 8);
    acc[0] = __builtin_amdgcn_mfma_f32_16x16x32_f16(a, b0, acc[0], 0, 0, 0);
    acc[1] = __builtin_amdgcn_mfma_f32_16x16x32_f16(a, b1, acc[1], 0, 0, 0);
  }
#pragma unroll
  for (int qj = 0; qj < 2; ++qj) {
    const int q = qj * 16 + (l & 15);
    const int row = sv * 16 + (l >> 4) * 4;
    *(f32x4*)&dst[(size_t)q * DH + row] = acc[qj];
  }
}

// ---------------------------------------------------------------------------
// Kernel G: per (b, 2 q):  T[v][k] = sum_n (E_n*V[n,v]) * K[n,k]  via MFMA.
// Double-buffered global_load_lds staging of fragment-linear tiles (no VALU,
// no bank conflicts); A-frags built in-register with v_pk_mul_f16.
// out = scale*invd*(T - invd*EV[v]*EK[k]) with EV/EK/denom precomputed.
// ---------------------------------------------------------------------------
__global__ __launch_bounds__(256, 2) void kjac(
    const f16* __restrict__ Vt, const f16* __restrict__ Kt,
    const f16* __restrict__ E, const float* __restrict__ EV,
    const float* __restrict__ EK, const float* __restrict__ denom,
    float* __restrict__ out) {
  __shared__ __align__(16) f16 Vl[2][4096];
  __shared__ __align__(16) f16 Kl[2][4096];

  const int blk = blockIdx.x;
  const int b = blk >> 5;
  const int q0 = (blk & 31) * 2;
  const int t = threadIdx.x, w = t >> 6, l = t & 63;
  const int sA = (w >> 1) * 4;  // A row-subtile base (quadrant)
  const int sB = (w & 1) * 4;   // B col-subtile base
  const char* vtb = (const char*)(Vt + (size_t)b * DH * SL);
  const char* ktb = (const char*)(Kt + (size_t)b * DH * SL);
  const f16* Eb = E + ((size_t)b * NQ + q0) * SL;

  f32x4 acc[2][4][4] = {};

#define STAGE(tile, buf)                                                      \
  {                                                                           \
    const size_t gb = (size_t)(tile)*8192 + w * 1024 + l * 16;                \
    gload16(vtb + gb, (char*)Vl[buf] + w * 1024 + l * 16);                    \
    gload16(vtb + gb + 4096, (char*)Vl[buf] + 4096 + w * 1024 + l * 16);      \
    gload16(ktb + gb, (char*)Kl[buf] + w * 1024 + l * 16);                    \
    gload16(ktb + gb + 4096, (char*)Kl[buf] + 4096 + w * 1024 + l * 16);      \
  }

  STAGE(0, 0)
  for (int tile = 0; tile < NT; ++tile) {
    const int cur = tile & 1;
    if (tile + 1 < NT) STAGE(tile + 1, cur ^ 1)
    __syncthreads();  // staged loads for `cur` drained here

    const int n0 = tile * 32;
    const half8 e0 = *(const half8*)(Eb + n0 + (l >> 4) * 8);
    const half8 e1 = *(const half8*)(Eb + SL + n0 + (l >> 4) * 8);
    const f16* vbuf = Vl[cur];
    const f16* kbuf = Kl[cur];
    half8 vf[4], kf[4];
#pragma unroll
    for (int i = 0; i < 4; ++i)
      vf[i] = *(const half8*)(vbuf + (sA + i) * 512 + l * 8);
#pragma unroll
    for (int j = 0; j < 4; ++j)
      kf[j] = *(const half8*)(kbuf + (sB + j) * 512 + l * 8);
#pragma unroll
    for (int i = 0; i < 4; ++i) {
      const half8 u0 = e0 * vf[i];  // v_pk_mul_f16 x4
      const half8 u1 = e1 * vf[i];
#pragma unroll
      for (int j = 0; j < 4; ++j) {
        acc[0][i][j] =
            __builtin_amdgcn_mfma_f32_16x16x32_f16(u0, kf[j], acc[0][i][j], 0, 0, 0);
        acc[1][i][j] =
            __builtin_amdgcn_mfma_f32_16x16x32_f16(u1, kf[j], acc[1][i][j], 0, 0, 0);
      }
    }
    __syncthreads();  // protect `cur^1` from next stage until reads done
  }
#undef STAGE

  const float scl = 0.08838834764831845f;
#pragma unroll
  for (int q = 0; q < 2; ++q) {
    const float invd = 1.0f / denom[b * NQ + q0 + q];
    const float* evq = EV + ((size_t)b * NQ + q0 + q) * DH;
    const float* ekq = EK + ((size_t)b * NQ + q0 + q) * DH;
    float* ob = out + (size_t)(b * NQ + q0 + q) * DH * DH;
#pragma unroll
    for (int i = 0; i < 4; ++i) {
      const int row0 = (sA + i) * 16 + (l >> 4) * 4;
      const f32x4 ev4 = *(const f32x4*)&evq[row0];
#pragma unroll
      for (int j = 0; j < 4; ++j) {
        const int col = (sB + j) * 16 + (l & 15);
        const float ek = ekq[col];
#pragma unroll
        for (int r = 0; r < 4; ++r)
          ob[(size_t)(row0 + r) * DH + col] =
              scl * invd * (acc[q][i][j][r] - invd * ev4[r] * ek);
      }
    }
  }
}

extern "C" void kernel_launch(void* const* d_in, const int* in_sizes, int n_in,
                              void* d_out, int out_size, void* d_ws,
                              size_t ws_size, hipStream_t stream) {
  const float* Q = (const float*)d_in[0];
  const float* K = (const float*)d_in[1];
  const float* V = (const float*)d_in[2];
  float* out = (float*)d_out;

  // ws: Vt 16.8MB | Kt 16.8MB | E f16 8.4MB | EV 0.5MB | EK 0.5MB | denom 4KB
  f16* Vt = (f16*)d_ws;
  f16* Kt = Vt + (size_t)BATCH * DH * SL;
  f16* Ef = Kt + (size_t)BATCH * DH * SL;
  float* EV = (float*)(Ef + (size_t)BATCH * NQ * SL);
  float* EK = EV + (size_t)BATCH * NQ * DH;
  float* denom = EK + (size_t)BATCH * NQ * DH;

  kprep<<<1024, 256, 0, stream>>>(K, V, Kt, Vt);
  kscore<<<512, 256, 0, stream>>>(Q, Kt, Ef);
  kreduce<<<256, 256, 0, stream>>>(Ef, denom);
  kev<<<128, 256, 0, stream>>>(Vt, Kt, Ef, EV, EK);
  kjac<<<512, 256, 0, stream>>>(Vt, Kt, Ef, EV, EK, denom, out);
}